// Round 11
// baseline (194.576 us; speedup 1.0000x reference)
//
#include <hip/hip_runtime.h>

// B=2, N=8192, K=10, I=3, LEN_IN=66. All buffers f32.
// LOCKED correctness recipe (R8-R10, passed, absmax 0.0625):
//   sq  = fmaf(z,z, fmaf(y,y, rn(x*x)))          (asc FMA)
//   dot = fmaf(z,z', fmaf(y,y', rn(x*x')))       (asc FMA)
//   d2  = fmaf(-2,dot, rn(sq_q + sq_c))          (== single-rounded sub form)
//   selection: strict <, stable lowest-index-first (lexicographic (d2,idx))
// R11: issue-density round. Candidates stream from GLOBAL (L2) with manual
// double-buffer prefetch; per-point sq precomputed once in LDS; push buffers
// transposed to [k][tid] (conflict-free b64); no VGPR cap (R10 spilled).
#define NPTS   8192
#define KNN    11
#define QPB    64          // queries per block (one per lane)
#define NTHR   512
#define NSLICE 8           // candidate slices (one per wave)
#define SLEN   (NPTS / NSLICE)   // 1024
#define DEPTH  12          // per-lane push-buffer entries
#define TRIG   9           // flush when any lane cnt >= TRIG (4 pushes headroom)

__global__ __launch_bounds__(NTHR) void knn_mlp(
    const float* __restrict__ pos,
    const float* __restrict__ vel,
    const float* __restrict__ initc,
    const float* __restrict__ W1,
    const float* __restrict__ b1,
    const float* __restrict__ W2,
    const float* __restrict__ b2,
    const float* __restrict__ W3,
    const float* __restrict__ b3,
    float* __restrict__ out) {

    __shared__ __align__(16) float ssq[NPTS];                 // 32KB per-point sq
    __shared__ __align__(16) unsigned long long region[NTHR * DEPTH]; // 48KB phased:
    // phase0: fold scratch (4.3KB) | phase1: push buffers [k][tid] | phase2: pd/pi (45KB)
    __shared__ float sW[405];                                 // Weff[396]+bias[6]+init[3]

    const int tid  = threadIdx.x;
    const int lane = tid & 63;
    const int wave = tid >> 6;
    const int b    = blockIdx.x >> 7;           // 128 blocks per batch
    const int n0   = (blockIdx.x & 127) * QPB;
    const int q    = n0 + lane;

    const float* posb = pos + b * NPTS * 3;
    const float* velb = vel + b * NPTS * 3;

    // ---- phase 1a: per-point sq into LDS (LOCKED recipe)
    for (int a = tid; a < NPTS; a += NTHR) {
        float x = posb[a * 3 + 0];
        float y = posb[a * 3 + 1];
        float z = posb[a * 3 + 2];
        ssq[a] = __fmaf_rn(z, z, __fmaf_rn(y, y, __fmul_rn(x, x)));
    }
    // ---- phase 1b: fold stage 1 (scratch in region): W12 = W1@W2, b12 = b1@W2+b2
    float* sW12 = (float*)region;
    for (int e = tid; e < 66 * 16; e += NTHR) {
        int r = e >> 4, c = e & 15;
        float s = 0.f;
        for (int j = 0; j < 32; ++j) s += W1[r * 32 + j] * W2[j * 16 + c];
        sW12[e] = s;
    }
    if (tid < 16) {
        float s = b2[tid];
        for (int j = 0; j < 32; ++j) s += b1[j] * W2[j * 16 + tid];
        sW12[66 * 16 + tid] = s;
    }
    if (tid < 3) sW[402 + tid] = initc[b * 3 + tid];
    __syncthreads();
    // ---- fold stage 2: Weff = W12@W3, bias = b12@W3 + b3
    for (int e = tid; e < 66 * 6; e += NTHR) {
        int r = e / 6, c = e - r * 6;
        float s = 0.f;
        for (int j = 0; j < 16; ++j) s += sW12[r * 16 + j] * W3[j * 6 + c];
        sW[e] = s;
    }
    if (tid < 6) {
        float s = b3[tid];
        for (int j = 0; j < 16; ++j) s += sW12[66 * 16 + j] * W3[j * 6 + tid];
        sW[396 + tid] = s;
    }
    __syncthreads();   // fold scratch done -> region becomes push buffers

    const float qx = posb[q * 3 + 0];
    const float qy = posb[q * 3 + 1];
    const float qz = posb[q * 3 + 2];
    const float sqq = ssq[q];           // identical bits to locked recipe

    float d[KNN]; int id[KNN];
#pragma unroll
    for (int m = 0; m < KNN; ++m) { d[m] = 3.0e38f; id[m] = 0x7FFFFFFF; }

    float thr = 3.0e38f;       // stale copy of d[10]; only over-buffers, never drops
    int cnt = 0;

    auto flush = [&]() {
#pragma unroll 1
        for (int k = 0; __any(k < cnt); ++k) {
            if (k < cnt) {
                unsigned long long e = region[k * NTHR + tid];   // [k][tid]: no conflicts
                float nd = __uint_as_float((unsigned)(e >> 32));
                int   nj = (int)(unsigned)(e & 0xFFFFFFFFull);
                if (nd < d[KNN - 1]) {          // strict <: stable
                    bool c = true;
#pragma unroll
                    for (int s = KNN - 1; s >= 1; --s) {
                        bool cp = nd < d[s - 1];
                        d[s]  = cp ? d[s - 1] : (c ? nd : d[s]);
                        id[s] = cp ? id[s - 1] : (c ? nj : id[s]);
                        c = cp;
                    }
                    if (c) { d[0] = nd; id[0] = nj; }
                }
            }
        }
        cnt = 0;
        thr = d[KNN - 1];
    };

    auto proc = [&](float cx, float cy, float cz, float sqc, int j) {
        float dot = __fmaf_rn(qz, cz, __fmaf_rn(qy, cy, __fmul_rn(qx, cx)));
        float d2  = __fmaf_rn(-2.0f, dot, __fadd_rn(sqq, sqc)); // == rn(s-2dot)
        if (d2 < thr) {
            region[cnt * NTHR + tid] =
                (((unsigned long long)__float_as_uint(d2)) << 32) | (unsigned)j;
            ++cnt;
        }
    };

    // ---- scan: wave streams its 1024-candidate slice from global (L2-hot),
    // manual double-buffer so next iteration's loads are in flight.
    const int base = wave * SLEN;
    const float4* gp = (const float4*)(posb + base * 3);  // 3 float4 per 4 cands
    const float4* sp = (const float4*)(ssq + base);
    float4 A = gp[0], Bv = gp[1], C = gp[2];
    float4 S = sp[0];
    for (int m = 0; m < SLEN; m += 4) {
        int mn = (m + 4 < SLEN) ? (m + 4) : 0;            // wrap: value unused
        int fi = (mn >> 2) * 3;
        float4 nA = gp[fi], nB = gp[fi + 1], nC = gp[fi + 2];
        float4 nS = sp[mn >> 2];
        int j = base + m;
        proc(A.x,  A.y,  A.z,  S.x, j + 0);
        proc(A.w,  Bv.x, Bv.y, S.y, j + 1);
        proc(Bv.z, Bv.w, C.x,  S.z, j + 2);
        proc(C.y,  C.z,  C.w,  S.w, j + 3);
        if (__any(cnt >= TRIG)) flush();                  // rare wave-uniform path
        A = nA; Bv = nB; C = nC; S = nS;
    }
    flush();

    __syncthreads();   // scans done -> region becomes merge lists
    float* pd = (float*)region;                     // [NTHR][11] f32
    int*   pi = (int*)(pd + NTHR * KNN);            // [NTHR][11] i32
#pragma unroll
    for (int m = 0; m < KNN; ++m) { pd[tid * KNN + m] = d[m]; pi[tid * KNN + m] = id[m]; }
    __syncthreads();

    if (tid < QPB) {
        // 8-way merge, lexicographic (d2, idx) == global stable top-11.
        int p[NSLICE]; float hd[NSLICE]; int hi[NSLICE];
#pragma unroll
        for (int s = 0; s < NSLICE; ++s) {
            p[s]  = 0;
            hd[s] = pd[(s * 64 + tid) * KNN];
            hi[s] = pi[(s * 64 + tid) * KNN];
        }
        float acc[6];
#pragma unroll
        for (int c = 0; c < 6; ++c) acc[c] = sW[396 + c];

        for (int r = 0; r < KNN; ++r) {
            float bd = 3.9e38f; int bi = 0x7FFFFFFF; int bs = 0;
#pragma unroll
            for (int s = 0; s < NSLICE; ++s) {
                bool better = (hd[s] < bd) || (hd[s] == bd && hi[s] < bi);
                bs = better ? s : bs;
                bi = better ? hi[s] : bi;
                bd = better ? hd[s] : bd;
            }
            {   // advance winning slice head
                int pp = ++p[bs];
                if (pp < KNN) {
                    hd[bs] = pd[(bs * 64 + tid) * KNN + pp];
                    hi[bs] = pi[(bs * 64 + tid) * KNN + pp];
                } else { hd[bs] = 3.9e38f; hi[bs] = 0x7FFFFFFF; }
            }

            int bg = ((unsigned)bi < (unsigned)NPTS) ? bi : 0;   // defensive

            // velocity features: slots [r*3 .. r*3+2]
            const float* vp = velb + bg * 3;
            float vx = vp[0], vy = vp[1], vz = vp[2];
            const float* w = &sW[r * 18];
#pragma unroll
            for (int c = 0; c < 6; ++c) {
                acc[c] += vx * w[c];
                acc[c] += vy * w[6 + c];
                acc[c] += vz * w[12 + c];
            }
            // offset features (positions from global, L2-hot): rank 0 = self
            if (r >= 1) {
                float ox = posb[bg * 3 + 0] - qx;
                float oy = posb[bg * 3 + 1] - qy;
                float oz = posb[bg * 3 + 2] - qz;
                const float* w2 = &sW[(33 + (r - 1) * 3) * 6];
#pragma unroll
                for (int c = 0; c < 6; ++c) {
                    acc[c] += ox * w2[c];
                    acc[c] += oy * w2[6 + c];
                    acc[c] += oz * w2[12 + c];
                }
            }
        }
        // init_config features: slots [63..65]
#pragma unroll
        for (int k3 = 0; k3 < 3; ++k3) {
            const float* w3 = &sW[(63 + k3) * 6];
            float iv = sW[402 + k3];
#pragma unroll
            for (int c = 0; c < 6; ++c) acc[c] += iv * w3[c];
        }
        acc[0] += qx; acc[1] += qy; acc[2] += qz;

        float* op = out + (b * NPTS + q) * 6;
#pragma unroll
        for (int c = 0; c < 6; ++c) op[c] = acc[c];
    }
}

extern "C" void kernel_launch(void* const* d_in, const int* in_sizes, int n_in,
                              void* d_out, int out_size, void* d_ws, size_t ws_size,
                              hipStream_t stream) {
    (void)in_sizes; (void)n_in; (void)out_size; (void)d_ws; (void)ws_size;
    const float* pos   = (const float*)d_in[0];
    const float* vel   = (const float*)d_in[1];
    const float* initc = (const float*)d_in[2];
    const float* W1    = (const float*)d_in[3];
    const float* b1    = (const float*)d_in[4];
    const float* W2    = (const float*)d_in[5];
    const float* b2    = (const float*)d_in[6];
    const float* W3    = (const float*)d_in[7];
    const float* b3    = (const float*)d_in[8];
    float* out = (float*)d_out;

    knn_mlp<<<256, NTHR, 0, stream>>>(pos, vel, initc, W1, b1, W2, b2, W3, b3, out);
}

// Round 12
// 176.875 us; speedup vs baseline: 1.1001x; 1.1001x over previous
//
#include <hip/hip_runtime.h>

// B=2, N=8192, K=10, I=3, LEN_IN=66. All buffers f32.
// LOCKED correctness recipe (R8-R11, passed, absmax 0.0625):
//   sq  = fmaf(z,z, fmaf(y,y, rn(x*x)))          (asc FMA)
//   dot = fmaf(z,z', fmaf(y,y', rn(x*x')))       (asc FMA)
//   d2  = fmaf(-2,dot, rn(sq_q + sq_c))          (== single-rounded sub form)
//   selection: strict <, stable lowest-index-first (lexicographic (d2,idx))
// R12: occupancy round. 1024-thread blocks -> 16 waves/block = 4 waves/SIMD
// (R11 was 2/SIMD, VALUBusy 48% = latency-bound). Manual prefetch dropped to
// fit the 128-VGPR cap spill-free (R10/R11 spilled 11.2MB scratch). 16 slices,
// 16-way merge. Push buffers stay [k][tid] (R11: conflicts 2.0M -> 38k).
#define NPTS   8192
#define KNN    11
#define QPB    64          // queries per block (one per lane)
#define NTHR   1024
#define NSLICE 16          // candidate slices (one per wave)
#define SLEN   (NPTS / NSLICE)   // 512
#define DEPTH  10          // per-lane push-buffer entries
#define TRIG   7           // flush when any lane cnt >= TRIG (4 pushes headroom)

__global__ __launch_bounds__(NTHR) void knn_mlp(
    const float* __restrict__ pos,
    const float* __restrict__ vel,
    const float* __restrict__ initc,
    const float* __restrict__ W1,
    const float* __restrict__ b1,
    const float* __restrict__ W2,
    const float* __restrict__ b2,
    const float* __restrict__ W3,
    const float* __restrict__ b3,
    float* __restrict__ out) {

    // Phased LDS (112KB):
    //   phase-scan : [0,32K) ssq | [32K,112K) push region [k][tid] u64
    //   phase-fold : [32K, ...) fold scratch (4.3KB)
    //   phase-merge: [0,45K) pd f32 | [45K,90K) pi i32   (ssq/region dead)
    __shared__ __align__(16) char smem[32 * 1024 + NTHR * DEPTH * 8];
    __shared__ float sW[405];           // Weff[396] + bias[6] + init[3]

    float* ssq = (float*)smem;
    unsigned long long* region = (unsigned long long*)(smem + 32 * 1024);

    const int tid  = threadIdx.x;
    const int lane = tid & 63;
    const int wave = tid >> 6;
    const int b    = blockIdx.x >> 7;           // 128 blocks per batch
    const int n0   = (blockIdx.x & 127) * QPB;
    const int q    = n0 + lane;

    const float* posb = pos + b * NPTS * 3;
    const float* velb = vel + b * NPTS * 3;

    // ---- phase 1a: per-point sq into LDS (LOCKED recipe)
    for (int a = tid; a < NPTS; a += NTHR) {
        float x = posb[a * 3 + 0];
        float y = posb[a * 3 + 1];
        float z = posb[a * 3 + 2];
        ssq[a] = __fmaf_rn(z, z, __fmaf_rn(y, y, __fmul_rn(x, x)));
    }
    // ---- phase 1b: fold stage 1 (scratch in region): W12 = W1@W2, b12 = b1@W2+b2
    float* sW12 = (float*)region;
    for (int e = tid; e < 66 * 16; e += NTHR) {
        int r = e >> 4, c = e & 15;
        float s = 0.f;
        for (int j = 0; j < 32; ++j) s += W1[r * 32 + j] * W2[j * 16 + c];
        sW12[e] = s;
    }
    if (tid < 16) {
        float s = b2[tid];
        for (int j = 0; j < 32; ++j) s += b1[j] * W2[j * 16 + tid];
        sW12[66 * 16 + tid] = s;
    }
    if (tid < 3) sW[402 + tid] = initc[b * 3 + tid];
    __syncthreads();
    // ---- fold stage 2: Weff = W12@W3, bias = b12@W3 + b3
    for (int e = tid; e < 66 * 6; e += NTHR) {
        int r = e / 6, c = e - r * 6;
        float s = 0.f;
        for (int j = 0; j < 16; ++j) s += sW12[r * 16 + j] * W3[j * 6 + c];
        sW[e] = s;
    }
    if (tid < 6) {
        float s = b3[tid];
        for (int j = 0; j < 16; ++j) s += sW12[66 * 16 + j] * W3[j * 6 + tid];
        sW[396 + tid] = s;
    }
    __syncthreads();   // fold scratch done -> region becomes push buffers

    const float qx = posb[q * 3 + 0];
    const float qy = posb[q * 3 + 1];
    const float qz = posb[q * 3 + 2];
    const float sqq = ssq[q];           // identical bits to locked recipe

    float d[KNN]; int id[KNN];
#pragma unroll
    for (int m = 0; m < KNN; ++m) { d[m] = 3.0e38f; id[m] = 0x7FFFFFFF; }

    float thr = 3.0e38f;       // stale copy of d[10]; only over-buffers, never drops
    int cnt = 0;

    auto flush = [&]() {
#pragma unroll 1
        for (int k = 0; __any(k < cnt); ++k) {
            if (k < cnt) {
                unsigned long long e = region[k * NTHR + tid];  // [k][tid]: 2-way only
                float nd = __uint_as_float((unsigned)(e >> 32));
                int   nj = (int)(unsigned)(e & 0xFFFFFFFFull);
                if (nd < d[KNN - 1]) {          // strict <: stable
                    bool c = true;
#pragma unroll
                    for (int s = KNN - 1; s >= 1; --s) {
                        bool cp = nd < d[s - 1];
                        d[s]  = cp ? d[s - 1] : (c ? nd : d[s]);
                        id[s] = cp ? id[s - 1] : (c ? nj : id[s]);
                        c = cp;
                    }
                    if (c) { d[0] = nd; id[0] = nj; }
                }
            }
        }
        cnt = 0;
        thr = d[KNN - 1];
    };

    auto proc = [&](float cx, float cy, float cz, float sqc, int j) {
        float dot = __fmaf_rn(qz, cz, __fmaf_rn(qy, cy, __fmul_rn(qx, cx)));
        float d2  = __fmaf_rn(-2.0f, dot, __fadd_rn(sqq, sqc)); // == rn(s-2dot)
        if (d2 < thr) {
            region[cnt * NTHR + tid] =
                (((unsigned long long)__float_as_uint(d2)) << 32) | (unsigned)j;
            ++cnt;
        }
    };

    // ---- scan: wave streams its 512-candidate slice from global (L2-hot);
    // 4 waves/SIMD provide the latency hiding (no manual prefetch -> low VGPR).
    const int base = wave * SLEN;
    const float4* gp = (const float4*)(posb + base * 3);  // 3 float4 per 4 cands
    const float4* sp = (const float4*)(ssq + base);
#pragma unroll 1
    for (int m = 0; m < SLEN; m += 4) {
        int f = (m >> 2) * 3;
        float4 A = gp[f], Bv = gp[f + 1], C = gp[f + 2];
        float4 S = sp[m >> 2];
        int j = base + m;
        proc(A.x,  A.y,  A.z,  S.x, j + 0);
        proc(A.w,  Bv.x, Bv.y, S.y, j + 1);
        proc(Bv.z, Bv.w, C.x,  S.z, j + 2);
        proc(C.y,  C.z,  C.w,  S.w, j + 3);
        if (__any(cnt >= TRIG)) flush();                  // rare wave-uniform path
    }
    flush();

    __syncthreads();   // scans done -> smem becomes merge lists
    float* pd = (float*)smem;                       // [NTHR][11] f32
    int*   pi = (int*)(smem + NTHR * KNN * 4);      // [NTHR][11] i32
#pragma unroll
    for (int m = 0; m < KNN; ++m) { pd[tid * KNN + m] = d[m]; pi[tid * KNN + m] = id[m]; }
    __syncthreads();

    if (tid < QPB) {
        // 16-way merge, lexicographic (d2, idx) == global stable top-11.
        int p[NSLICE]; float hd[NSLICE]; int hi[NSLICE];
#pragma unroll
        for (int s = 0; s < NSLICE; ++s) {
            p[s]  = 0;
            hd[s] = pd[(s * 64 + tid) * KNN];
            hi[s] = pi[(s * 64 + tid) * KNN];
        }
        float acc[6];
#pragma unroll
        for (int c = 0; c < 6; ++c) acc[c] = sW[396 + c];

        for (int r = 0; r < KNN; ++r) {
            float bd = 3.9e38f; int bi = 0x7FFFFFFF; int bs = 0;
#pragma unroll
            for (int s = 0; s < NSLICE; ++s) {
                bool better = (hd[s] < bd) || (hd[s] == bd && hi[s] < bi);
                bs = better ? s : bs;
                bi = better ? hi[s] : bi;
                bd = better ? hd[s] : bd;
            }
            {   // advance winning slice head
                int pp = ++p[bs];
                if (pp < KNN) {
                    hd[bs] = pd[(bs * 64 + tid) * KNN + pp];
                    hi[bs] = pi[(bs * 64 + tid) * KNN + pp];
                } else { hd[bs] = 3.9e38f; hi[bs] = 0x7FFFFFFF; }
            }

            int bg = ((unsigned)bi < (unsigned)NPTS) ? bi : 0;   // defensive

            // velocity features: slots [r*3 .. r*3+2]
            const float* vp = velb + bg * 3;
            float vx = vp[0], vy = vp[1], vz = vp[2];
            const float* w = &sW[r * 18];
#pragma unroll
            for (int c = 0; c < 6; ++c) {
                acc[c] += vx * w[c];
                acc[c] += vy * w[6 + c];
                acc[c] += vz * w[12 + c];
            }
            // offset features (positions from global, L2-hot): rank 0 = self
            if (r >= 1) {
                float ox = posb[bg * 3 + 0] - qx;
                float oy = posb[bg * 3 + 1] - qy;
                float oz = posb[bg * 3 + 2] - qz;
                const float* w2 = &sW[(33 + (r - 1) * 3) * 6];
#pragma unroll
                for (int c = 0; c < 6; ++c) {
                    acc[c] += ox * w2[c];
                    acc[c] += oy * w2[6 + c];
                    acc[c] += oz * w2[12 + c];
                }
            }
        }
        // init_config features: slots [63..65]
#pragma unroll
        for (int k3 = 0; k3 < 3; ++k3) {
            const float* w3 = &sW[(63 + k3) * 6];
            float iv = sW[402 + k3];
#pragma unroll
            for (int c = 0; c < 6; ++c) acc[c] += iv * w3[c];
        }
        acc[0] += qx; acc[1] += qy; acc[2] += qz;

        float* op = out + (b * NPTS + q) * 6;
#pragma unroll
        for (int c = 0; c < 6; ++c) op[c] = acc[c];
    }
}

extern "C" void kernel_launch(void* const* d_in, const int* in_sizes, int n_in,
                              void* d_out, int out_size, void* d_ws, size_t ws_size,
                              hipStream_t stream) {
    (void)in_sizes; (void)n_in; (void)out_size; (void)d_ws; (void)ws_size;
    const float* pos   = (const float*)d_in[0];
    const float* vel   = (const float*)d_in[1];
    const float* initc = (const float*)d_in[2];
    const float* W1    = (const float*)d_in[3];
    const float* b1    = (const float*)d_in[4];
    const float* W2    = (const float*)d_in[5];
    const float* b2    = (const float*)d_in[6];
    const float* W3    = (const float*)d_in[7];
    const float* b3    = (const float*)d_in[8];
    float* out = (float*)d_out;

    knn_mlp<<<256, NTHR, 0, stream>>>(pos, vel, initc, W1, b1, W2, b2, W3, b3, out);
}

// Round 13
// 175.317 us; speedup vs baseline: 1.1099x; 1.0089x over previous
//
#include <hip/hip_runtime.h>

// B=2, N=8192, K=10, I=3, LEN_IN=66. All buffers f32.
// LOCKED correctness recipe (R8-R12, passed, absmax 0.0625):
//   sq  = fmaf(z,z, fmaf(y,y, rn(x*x)))          (asc FMA)
//   dot = fmaf(z,z', fmaf(y,y', rn(x*x')))       (asc FMA)
//   d2  = fmaf(-2,dot, rn(sq_q + sq_c))          (== single-rounded sub form)
//   selection: strict <, stable lowest-index-first (lexicographic (d2,idx))
// R13: register-residency round. R12's VGPR_Count=52 proved the compiler
// demoted d[11]/id[11] to scratch (each flush entry = ~44 scratch ops).
// Fix: 22 named scalars + hand-unrolled cndmask insert chain (bit-identical
// semantics), __launch_bounds__(1024,4) so the allocator targets 128 VGPR.
#define NPTS   8192
#define KNN    11
#define QPB    64          // queries per block (one per lane)
#define NTHR   1024
#define NSLICE 16          // candidate slices (one per wave)
#define SLEN   (NPTS / NSLICE)   // 512
#define DEPTH  10          // per-lane push-buffer entries
#define TRIG   7           // flush when any lane cnt >= TRIG (4 pushes headroom)

__global__ __launch_bounds__(NTHR, 4) void knn_mlp(
    const float* __restrict__ pos,
    const float* __restrict__ vel,
    const float* __restrict__ initc,
    const float* __restrict__ W1,
    const float* __restrict__ b1,
    const float* __restrict__ W2,
    const float* __restrict__ b2,
    const float* __restrict__ W3,
    const float* __restrict__ b3,
    float* __restrict__ out) {

    // Phased LDS (112KB):
    //   phase-scan : [0,32K) ssq | [32K,112K) push region [k][tid] u64
    //   phase-fold : [32K, ...) fold scratch (4.3KB)
    //   phase-merge: [0,45K) pd f32 | [45K,90K) pi i32   (ssq/region dead)
    __shared__ __align__(16) char smem[32 * 1024 + NTHR * DEPTH * 8];
    __shared__ float sW[405];           // Weff[396] + bias[6] + init[3]

    float* ssq = (float*)smem;
    unsigned long long* region = (unsigned long long*)(smem + 32 * 1024);

    const int tid  = threadIdx.x;
    const int lane = tid & 63;
    const int wave = tid >> 6;
    const int b    = blockIdx.x >> 7;           // 128 blocks per batch
    const int n0   = (blockIdx.x & 127) * QPB;
    const int q    = n0 + lane;

    const float* posb = pos + b * NPTS * 3;
    const float* velb = vel + b * NPTS * 3;

    // ---- phase 1a: per-point sq into LDS (LOCKED recipe)
    for (int a = tid; a < NPTS; a += NTHR) {
        float x = posb[a * 3 + 0];
        float y = posb[a * 3 + 1];
        float z = posb[a * 3 + 2];
        ssq[a] = __fmaf_rn(z, z, __fmaf_rn(y, y, __fmul_rn(x, x)));
    }
    // ---- phase 1b: fold stage 1 (scratch in region): W12 = W1@W2, b12 = b1@W2+b2
    float* sW12 = (float*)region;
    for (int e = tid; e < 66 * 16; e += NTHR) {
        int r = e >> 4, c = e & 15;
        float s = 0.f;
        for (int j = 0; j < 32; ++j) s += W1[r * 32 + j] * W2[j * 16 + c];
        sW12[e] = s;
    }
    if (tid < 16) {
        float s = b2[tid];
        for (int j = 0; j < 32; ++j) s += b1[j] * W2[j * 16 + tid];
        sW12[66 * 16 + tid] = s;
    }
    if (tid < 3) sW[402 + tid] = initc[b * 3 + tid];
    __syncthreads();
    // ---- fold stage 2: Weff = W12@W3, bias = b12@W3 + b3
    for (int e = tid; e < 66 * 6; e += NTHR) {
        int r = e / 6, c = e - r * 6;
        float s = 0.f;
        for (int j = 0; j < 16; ++j) s += sW12[r * 16 + j] * W3[j * 6 + c];
        sW[e] = s;
    }
    if (tid < 6) {
        float s = b3[tid];
        for (int j = 0; j < 16; ++j) s += sW12[66 * 16 + j] * W3[j * 6 + tid];
        sW[396 + tid] = s;
    }
    __syncthreads();   // fold scratch done -> region becomes push buffers

    const float qx = posb[q * 3 + 0];
    const float qy = posb[q * 3 + 1];
    const float qz = posb[q * 3 + 2];
    const float sqq = ssq[q];           // identical bits to locked recipe

    // Top-11 in NAMED SCALARS (forced register residency; R12 demoted arrays).
    float d0 = 3.0e38f, d1 = 3.0e38f, d2v = 3.0e38f, d3 = 3.0e38f, d4 = 3.0e38f,
          d5 = 3.0e38f, d6 = 3.0e38f, d7 = 3.0e38f, d8 = 3.0e38f, d9 = 3.0e38f,
          d10 = 3.0e38f;
    int   i0 = 0x7FFFFFFF, i1 = 0x7FFFFFFF, i2v = 0x7FFFFFFF, i3 = 0x7FFFFFFF,
          i4 = 0x7FFFFFFF, i5 = 0x7FFFFFFF, i6 = 0x7FFFFFFF, i7 = 0x7FFFFFFF,
          i8 = 0x7FFFFFFF, i9 = 0x7FFFFFFF, i10 = 0x7FFFFFFF;

    float thr = 3.0e38f;       // stale copy of d10; only over-buffers, never drops
    int cnt = 0;

    // Hand-unrolled stable insert (identical semantics to the array loop).
    auto insert = [&](float nd, int nj) {
        if (nd < d10) {
            bool c, cp;
            cp = nd < d9;  d10 = cp ? d9  : nd;             i10 = cp ? i9  : nj;             c = cp;
            cp = nd < d8;  d9  = cp ? d8  : (c ? nd : d9);  i9  = cp ? i8  : (c ? nj : i9);  c = cp;
            cp = nd < d7;  d8  = cp ? d7  : (c ? nd : d8);  i8  = cp ? i7  : (c ? nj : i8);  c = cp;
            cp = nd < d6;  d7  = cp ? d6  : (c ? nd : d7);  i7  = cp ? i6  : (c ? nj : i7);  c = cp;
            cp = nd < d5;  d6  = cp ? d5  : (c ? nd : d6);  i6  = cp ? i5  : (c ? nj : i6);  c = cp;
            cp = nd < d4;  d5  = cp ? d4  : (c ? nd : d5);  i5  = cp ? i4  : (c ? nj : i5);  c = cp;
            cp = nd < d3;  d4  = cp ? d3  : (c ? nd : d4);  i4  = cp ? i3  : (c ? nj : i4);  c = cp;
            cp = nd < d2v; d3  = cp ? d2v : (c ? nd : d3);  i3  = cp ? i2v : (c ? nj : i3);  c = cp;
            cp = nd < d1;  d2v = cp ? d1  : (c ? nd : d2v); i2v = cp ? i1  : (c ? nj : i2v); c = cp;
            cp = nd < d0;  d1  = cp ? d0  : (c ? nd : d1);  i1  = cp ? i0  : (c ? nj : i1);  c = cp;
            if (c) { d0 = nd; i0 = nj; }
        }
    };

    auto flush = [&]() {
#pragma unroll 1
        for (int k = 0; __any(k < cnt); ++k) {
            if (k < cnt) {
                unsigned long long e = region[k * NTHR + tid];  // [k][tid]: 2-way only
                float nd = __uint_as_float((unsigned)(e >> 32));
                int   nj = (int)(unsigned)(e & 0xFFFFFFFFull);
                insert(nd, nj);
            }
        }
        cnt = 0;
        thr = d10;
    };

    auto proc = [&](float cx, float cy, float cz, float sqc, int j) {
        float dot = __fmaf_rn(qz, cz, __fmaf_rn(qy, cy, __fmul_rn(qx, cx)));
        float dd  = __fmaf_rn(-2.0f, dot, __fadd_rn(sqq, sqc)); // == rn(s-2dot)
        if (dd < thr) {
            region[cnt * NTHR + tid] =
                (((unsigned long long)__float_as_uint(dd)) << 32) | (unsigned)j;
            ++cnt;
        }
    };

    // ---- scan: wave streams its 512-candidate slice from global (L2-hot).
    const int base = wave * SLEN;
    const float4* gp = (const float4*)(posb + base * 3);  // 3 float4 per 4 cands
    const float4* sp = (const float4*)(ssq + base);
#pragma unroll 1
    for (int m = 0; m < SLEN; m += 4) {
        int f = (m >> 2) * 3;
        float4 A = gp[f], Bv = gp[f + 1], C = gp[f + 2];
        float4 S = sp[m >> 2];
        int j = base + m;
        proc(A.x,  A.y,  A.z,  S.x, j + 0);
        proc(A.w,  Bv.x, Bv.y, S.y, j + 1);
        proc(Bv.z, Bv.w, C.x,  S.z, j + 2);
        proc(C.y,  C.z,  C.w,  S.w, j + 3);
        if (__any(cnt >= TRIG)) flush();                  // rare wave-uniform path
    }
    flush();

    __syncthreads();   // scans done -> smem becomes merge lists
    float* pd = (float*)smem;                       // [NTHR][11] f32
    int*   pi = (int*)(smem + NTHR * KNN * 4);      // [NTHR][11] i32
    {
        float* pw = pd + tid * KNN;
        int*   iw = pi + tid * KNN;
        pw[0] = d0;  pw[1] = d1;  pw[2] = d2v; pw[3] = d3;  pw[4] = d4;
        pw[5] = d5;  pw[6] = d6;  pw[7] = d7;  pw[8] = d8;  pw[9] = d9;
        pw[10] = d10;
        iw[0] = i0;  iw[1] = i1;  iw[2] = i2v; iw[3] = i3;  iw[4] = i4;
        iw[5] = i5;  iw[6] = i6;  iw[7] = i7;  iw[8] = i8;  iw[9] = i9;
        iw[10] = i10;
    }
    __syncthreads();

    if (tid < QPB) {
        // 16-way merge, lexicographic (d2, idx) == global stable top-11.
        int p[NSLICE]; float hd[NSLICE]; int hi[NSLICE];
#pragma unroll
        for (int s = 0; s < NSLICE; ++s) {
            p[s]  = 0;
            hd[s] = pd[(s * 64 + tid) * KNN];
            hi[s] = pi[(s * 64 + tid) * KNN];
        }
        float acc[6];
#pragma unroll
        for (int c = 0; c < 6; ++c) acc[c] = sW[396 + c];

        for (int r = 0; r < KNN; ++r) {
            float bd = 3.9e38f; int bi = 0x7FFFFFFF; int bs = 0;
#pragma unroll
            for (int s = 0; s < NSLICE; ++s) {
                bool better = (hd[s] < bd) || (hd[s] == bd && hi[s] < bi);
                bs = better ? s : bs;
                bi = better ? hi[s] : bi;
                bd = better ? hd[s] : bd;
            }
            {   // advance winning slice head
                int pp = ++p[bs];
                if (pp < KNN) {
                    hd[bs] = pd[(bs * 64 + tid) * KNN + pp];
                    hi[bs] = pi[(bs * 64 + tid) * KNN + pp];
                } else { hd[bs] = 3.9e38f; hi[bs] = 0x7FFFFFFF; }
            }

            int bg = ((unsigned)bi < (unsigned)NPTS) ? bi : 0;   // defensive

            // velocity features: slots [r*3 .. r*3+2]
            const float* vp = velb + bg * 3;
            float vx = vp[0], vy = vp[1], vz = vp[2];
            const float* w = &sW[r * 18];
#pragma unroll
            for (int c = 0; c < 6; ++c) {
                acc[c] += vx * w[c];
                acc[c] += vy * w[6 + c];
                acc[c] += vz * w[12 + c];
            }
            // offset features (positions from global, L2-hot): rank 0 = self
            if (r >= 1) {
                float ox = posb[bg * 3 + 0] - qx;
                float oy = posb[bg * 3 + 1] - qy;
                float oz = posb[bg * 3 + 2] - qz;
                const float* w2 = &sW[(33 + (r - 1) * 3) * 6];
#pragma unroll
                for (int c = 0; c < 6; ++c) {
                    acc[c] += ox * w2[c];
                    acc[c] += oy * w2[6 + c];
                    acc[c] += oz * w2[12 + c];
                }
            }
        }
        // init_config features: slots [63..65]
#pragma unroll
        for (int k3 = 0; k3 < 3; ++k3) {
            const float* w3 = &sW[(63 + k3) * 6];
            float iv = sW[402 + k3];
#pragma unroll
            for (int c = 0; c < 6; ++c) acc[c] += iv * w3[c];
        }
        acc[0] += qx; acc[1] += qy; acc[2] += qz;

        float* op = out + (b * NPTS + q) * 6;
#pragma unroll
        for (int c = 0; c < 6; ++c) op[c] = acc[c];
    }
}

extern "C" void kernel_launch(void* const* d_in, const int* in_sizes, int n_in,
                              void* d_out, int out_size, void* d_ws, size_t ws_size,
                              hipStream_t stream) {
    (void)in_sizes; (void)n_in; (void)out_size; (void)d_ws; (void)ws_size;
    const float* pos   = (const float*)d_in[0];
    const float* vel   = (const float*)d_in[1];
    const float* initc = (const float*)d_in[2];
    const float* W1    = (const float*)d_in[3];
    const float* b1    = (const float*)d_in[4];
    const float* W2    = (const float*)d_in[5];
    const float* b2    = (const float*)d_in[6];
    const float* W3    = (const float*)d_in[7];
    const float* b3    = (const float*)d_in[8];
    float* out = (float*)d_out;

    knn_mlp<<<256, NTHR, 0, stream>>>(pos, vel, initc, W1, b1, W2, b2, W3, b3, out);
}